// Round 3
// baseline (555.471 us; speedup 1.0000x reference)
//
#include <hip/hip_runtime.h>
#include <cstdint>

typedef __fp16 f16x8 __attribute__((ext_vector_type(8)));
typedef __fp16 f16x4 __attribute__((ext_vector_type(4)));
typedef float  f32x4 __attribute__((ext_vector_type(4)));

static constexpr int NDIM = 1024;  // N = H*W = C = KC = VC

// ---------------- workspace layout (bytes) ----------------
static constexpr long long OFF_W     = 0;
static constexpr long long OFF_BIAS  = 6291456;
static constexpr long long OFF_XT    = 6303744;
static constexpr long long OFF_S     = 0;
static constexpr long long OFF_QKV   = 134217728;
static constexpr long long OFF_STATS = OFF_QKV + 2097152;  // over k[0]
// total required: OFF_QKV + 32*3072*1024*2 = 335,544,320 bytes

__device__ __forceinline__ void async16(__fp16* lds, const __fp16* g) {
  __builtin_amdgcn_global_load_lds(
      (const __attribute__((address_space(1))) void*)g,
      (__attribute__((address_space(3))) void*)lds, 16, 0, 0);
}

// ---------------- small prep kernels ----------------
__global__ __launch_bounds__(256) void cast_w(const float* __restrict__ Wq,
                                              const float* __restrict__ Wk,
                                              const float* __restrict__ Wv,
                                              __fp16* __restrict__ W3) {
  const int i = blockIdx.x * 256 + threadIdx.x;
  const int which = i >> 18;
  const int j = i & 262143;
  const float* src = which == 0 ? Wq : (which == 1 ? Wk : Wv);
  const float4 v = ((const float4*)src)[j];
  f16x4 o = {(__fp16)v.x, (__fp16)v.y, (__fp16)v.z, (__fp16)v.w};
  ((f16x4*)W3)[i] = o;
}

__global__ __launch_bounds__(256) void pack_bias(const float* __restrict__ bq,
                                                 const float* __restrict__ bk,
                                                 const float* __restrict__ bv,
                                                 float* __restrict__ b3) {
  const int i = blockIdx.x * 256 + threadIdx.x;
  if (i < 1024) b3[i] = bq[i];
  else if (i < 2048) b3[i] = bk[i - 1024];
  else if (i < 3072) b3[i] = bv[i - 2048];
}

__global__ __launch_bounds__(256) void transpose_cast_x(const float* __restrict__ x,
                                                        __fp16* __restrict__ xT) {
  __shared__ float t[32][33];
  const int b = blockIdx.z;
  const int n0 = blockIdx.x * 32, c0 = blockIdx.y * 32;
  const float* xb = x + (long long)b * NDIM * NDIM;
  __fp16* ob = xT + (long long)b * NDIM * NDIM;
  const int tx = threadIdx.x & 31, ty = threadIdx.x >> 5;
#pragma unroll
  for (int i = ty; i < 32; i += 8)
    t[i][tx] = xb[(long long)(c0 + i) * NDIM + n0 + tx];
  __syncthreads();
#pragma unroll
  for (int i = ty; i < 32; i += 8)
    ob[(long long)(n0 + i) * NDIM + c0 + tx] = (__fp16)t[tx][i];
}

// ---------------- 256x256 BK=32 quad-buffered gemm_bt (A[M][K] * B^T[N][K]) ----------------
// LDS: As/Bs [4 buf][256 rows][32 cols] fp16. 16B-slot swizzle: slot s holds
// source k-chunk s ^ ((row>>1)&3)  -> quarter-wave ds_read_b128 is 2-way (free).
// Pipeline: tile t reads buf t&3; during tile t, stage tile t+3 into buf (t+3)&3
// (dead since tile t-1's reads finished before tile t's top barrier).
// One counted wait per tile: vmcnt(8) = 2 tiles (8 loads) stay in flight. Never 0.

#define STAGE_A(NXT, KN)                                                            \
  async16(&As[(NXT)*8192 + tid*8],        A  + (long long)(m0 + sRow)       * 1024 + (KN) + sCol); \
  async16(&As[(NXT)*8192 + 4096 + tid*8], A  + (long long)(m0 + 128 + sRow) * 1024 + (KN) + sCol);

#define STAGE_B(NXT, KN)                                                            \
  async16(&Bs[(NXT)*8192 + tid*8],        Bp + (long long)(n0 + sRow)       * 1024 + (KN) + sCol); \
  async16(&Bs[(NXT)*8192 + 4096 + tid*8], Bp + (long long)(n0 + 128 + sRow) * 1024 + (KN) + sCol);

#define MFMA_PAIR(NF)                                                               \
  __builtin_amdgcn_s_setprio(1);                                                    \
  _Pragma("unroll")                                                                 \
  for (int mf = 0; mf < 8; ++mf) {                                                  \
    acc[mf][NF]     = __builtin_amdgcn_mfma_f32_16x16x32_f16(af[mf], bf[NF],     acc[mf][NF], 0, 0, 0);     \
    acc[mf][NF + 1] = __builtin_amdgcn_mfma_f32_16x16x32_f16(af[mf], bf[NF + 1], acc[mf][NF + 1], 0, 0, 0); \
  }                                                                                 \
  __builtin_amdgcn_s_setprio(0);                                                    \
  __builtin_amdgcn_sched_barrier(0);

#define TILE(BUF, NXT, KN)                                                          \
  asm volatile("s_waitcnt vmcnt(8)" ::: "memory");                                  \
  __builtin_amdgcn_s_barrier();                                                     \
  STAGE_A(NXT, KN)                                                                  \
  _Pragma("unroll")                                                                 \
  for (int mf = 0; mf < 8; ++mf)                                                    \
    af[mf] = *(const f16x8*)&As[(BUF)*8192 + aBase + mf*512];                       \
  bf[0] = *(const f16x8*)&Bs[(BUF)*8192 + bBase + 0*512];                           \
  bf[1] = *(const f16x8*)&Bs[(BUF)*8192 + bBase + 1*512];                           \
  __builtin_amdgcn_s_barrier();                                                     \
  MFMA_PAIR(0)                                                                      \
  __builtin_amdgcn_s_barrier();                                                     \
  STAGE_B(NXT, KN)                                                                  \
  bf[2] = *(const f16x8*)&Bs[(BUF)*8192 + bBase + 2*512];                           \
  bf[3] = *(const f16x8*)&Bs[(BUF)*8192 + bBase + 3*512];                           \
  __builtin_amdgcn_s_barrier();                                                     \
  MFMA_PAIR(2)

template <int EPI>
__global__ __launch_bounds__(512, 2)
void gemm256(const __fp16* __restrict__ Ag, const __fp16* __restrict__ Bg,
             void* __restrict__ Cout, const float* __restrict__ bias,
             const float* __restrict__ X, const float* __restrict__ gamma,
             long long sA, long long sB, long long sC) {
  __shared__ alignas(16) __fp16 As[4 * 8192];
  __shared__ alignas(16) __fp16 Bs[4 * 8192];

  const int tid  = threadIdx.x;
  const int wid  = tid >> 6, lane = tid & 63;
  const int wm   = wid >> 2, wn = wid & 3;
  const int g    = lane >> 4, r = lane & 15;
  const int b    = blockIdx.z;
  const int m0   = blockIdx.y * 256;
  const int n0   = blockIdx.x * 256;

  const __fp16* A  = Ag + (long long)b * sA;
  const __fp16* Bp = Bg + (long long)b * sB;

  // staging source pre-swizzle (LDS dest linear): slot tid&3 of row tid>>2
  // must hold source chunk (tid&3) ^ ((row>>1)&3); (row>>1)&3 == (tid>>3)&3.
  const int sRow = tid >> 2;
  const int sCol = ((tid & 3) ^ ((tid >> 3) & 3)) * 8;

  // fragment read offsets: k-chunk g of row R lives at slot g ^ ((R>>1)&3);
  // (R>>1)&3 == (r>>1)&3 for both A (R = wm*128+mf*16+r) and B (R = wn*64+nf*16+r).
  const int fcol  = (g ^ ((r >> 1) & 3)) * 8;
  const int aBase = (wm * 128 + r) * 32 + fcol;
  const int bBase = (wn * 64 + r) * 32 + fcol;

  f16x8 af[8];
  f16x8 bf[4];
  f32x4 acc[8][4];
#pragma unroll
  for (int i = 0; i < 8; ++i)
#pragma unroll
    for (int j = 0; j < 4; ++j) acc[i][j] = f32x4{0.f, 0.f, 0.f, 0.f};

  // prologue: stage tiles 0,1,2 into bufs 0,1,2 (A then B per tile -> queue [A,A,B,B]*)
  STAGE_A(0, 0)  STAGE_B(0, 0)
  STAGE_A(1, 32) STAGE_B(1, 32)
  STAGE_A(2, 64) STAGE_B(2, 64)

  for (int t0 = 0; t0 < 1024; t0 += 128) {  // 4 tiles (BK=32) per iteration
    const int ka  = t0 + 96;                // k of tile (t0/32)+3
    const int k0n = (ka < 1024) ? ka : 0;   // clamped prefetch: junk lands in a
    const int k1n = (ka + 32 < 1024) ? ka + 32 : 0;  // dead buffer, keeps vmcnt uniform
    const int k2n = (ka + 64 < 1024) ? ka + 64 : 0;
    const int k3n = (ka + 96 < 1024) ? ka + 96 : 0;
    TILE(0, 3, k0n)
    TILE(1, 0, k1n)
    TILE(2, 1, k2n)
    TILE(3, 2, k3n)
  }

  // epilogue: C/D layout col=lane&15, row=(lane>>4)*4+reg
  const float g2 = (EPI == 2) ? gamma[0] : 0.f;
  const int ccol  = n0 + wn * 64 + (lane & 15);
  const int crow0 = m0 + wm * 128 + (lane >> 4) * 4;
#pragma unroll
  for (int mf = 0; mf < 8; ++mf) {
#pragma unroll
    for (int reg = 0; reg < 4; ++reg) {
      const int row = crow0 + mf * 16 + reg;
      const long long rb = (long long)b * sC + (long long)row * 1024;
      const float bb = (EPI == 0) ? bias[row] : 0.f;
#pragma unroll
      for (int nf = 0; nf < 4; ++nf) {
        const int col = ccol + nf * 16;
        const float v = acc[mf][nf][reg];
        if (EPI == 0)      ((__fp16*)Cout)[rb + col] = (__fp16)(v + bb);
        else if (EPI == 1) ((float*)Cout)[rb + col] = v;
        else               ((float*)Cout)[rb + col] = g2 * v + X[rb + col];
      }
    }
  }
}

// ---------------- softmax ----------------
__global__ __launch_bounds__(256) void row_stats(const float* __restrict__ S,
                                                 float2* __restrict__ stats) {
  const int row = blockIdx.x * 4 + (threadIdx.x >> 6);
  const int lane = threadIdx.x & 63;
  const float4* rp = (const float4*)(S + (long long)row * NDIM);
  float4 v[4];
  float m = -3.4e38f;
#pragma unroll
  for (int j = 0; j < 4; j++) {
    v[j] = rp[lane + 64 * j];
    m = fmaxf(m, fmaxf(fmaxf(v[j].x, v[j].y), fmaxf(v[j].z, v[j].w)));
  }
#pragma unroll
  for (int o = 32; o; o >>= 1) m = fmaxf(m, __shfl_xor(m, o));
  float s = 0.f;
#pragma unroll
  for (int j = 0; j < 4; j++)
    s += __expf(v[j].x - m) + __expf(v[j].y - m) + __expf(v[j].z - m) + __expf(v[j].w - m);
#pragma unroll
  for (int o = 32; o; o >>= 1) s += __shfl_xor(s, o);
  if (lane == 0) stats[row] = make_float2(m, 1.f / s);
}

__global__ __launch_bounds__(256) void softmax_transpose(const float* __restrict__ S,
                                                         const float2* __restrict__ stats,
                                                         __fp16* __restrict__ attnT) {
  __shared__ __fp16 t[64][72];
  const int b = blockIdx.z;
  const int i0 = blockIdx.y * 64, j0 = blockIdx.x * 64;
  const float* Sb = S + (long long)b * NDIM * NDIM;
  const float2* st = stats + b * NDIM;
  const int tr = threadIdx.x >> 4;
  const int tc = (threadIdx.x & 15) * 4;
#pragma unroll
  for (int it = 0; it < 4; it++) {
    const int i = tr + 16 * it;
    const float4 vv = *(const float4*)&Sb[(long long)(i0 + i) * NDIM + j0 + tc];
    const float2 ms = st[i0 + i];
    t[tc + 0][i] = (__fp16)(__expf(vv.x - ms.x) * ms.y);
    t[tc + 1][i] = (__fp16)(__expf(vv.y - ms.x) * ms.y);
    t[tc + 2][i] = (__fp16)(__expf(vv.z - ms.x) * ms.y);
    t[tc + 3][i] = (__fp16)(__expf(vv.w - ms.x) * ms.y);
  }
  __syncthreads();
  __fp16* Ab = attnT + (long long)b * 3145728;
#pragma unroll
  for (int it = 0; it < 4; it++) {
    const int j = tr + 16 * it;
    f16x4 o = {t[j][tc], t[j][tc + 1], t[j][tc + 2], t[j][tc + 3]};
    *(f16x4*)&Ab[(long long)(j0 + j) * NDIM + i0 + tc] = o;
  }
}

// ---------------- launch ----------------
extern "C" void kernel_launch(void* const* d_in, const int* in_sizes, int n_in,
                              void* d_out, int out_size, void* d_ws, size_t ws_size,
                              hipStream_t stream) {
  const float* x     = (const float*)d_in[0];
  const float* Wq    = (const float*)d_in[1];
  const float* bq    = (const float*)d_in[2];
  const float* Wk    = (const float*)d_in[3];
  const float* bk    = (const float*)d_in[4];
  const float* Wv    = (const float*)d_in[5];
  const float* bv    = (const float*)d_in[6];
  const float* gamma = (const float*)d_in[7];
  char* ws = (char*)d_ws;

  __fp16* W3    = (__fp16*)(ws + OFF_W);
  float*  bias3 = (float*)(ws + OFF_BIAS);
  __fp16* xT    = (__fp16*)(ws + OFF_XT);
  float*  S     = (float*)(ws + OFF_S);
  __fp16* QKV   = (__fp16*)(ws + OFF_QKV);
  float2* stats = (float2*)(ws + OFF_STATS);
  float*  out   = (float*)d_out;

  cast_w<<<3072, 256, 0, stream>>>(Wq, Wk, Wv, W3);
  pack_bias<<<12, 256, 0, stream>>>(bq, bk, bv, bias3);
  transpose_cast_x<<<dim3(32, 32, 32), 256, 0, stream>>>(x, xT);

  // QKV[b] = W3 (3072x1024) * xT[b]^T  (+bias), fp16
  gemm256<0><<<dim3(4, 12, 32), 512, 0, stream>>>(
      W3, xT, QKV, bias3, nullptr, nullptr,
      0LL, 1048576LL, 3145728LL);

  // S[b] = q[b] * k[b]^T, f32
  gemm256<1><<<dim3(4, 4, 32), 512, 0, stream>>>(
      QKV, QKV + 1048576, S, nullptr, nullptr, nullptr,
      3145728LL, 3145728LL, 1048576LL);

  row_stats<<<8192, 256, 0, stream>>>(S, stats);
  softmax_transpose<<<dim3(16, 16, 32), 256, 0, stream>>>(S, stats, QKV);

  // out[b] = gamma * (v[b] * attnT[b]^T) + x[b], f32 -> d_out
  gemm256<2><<<dim3(4, 4, 32), 512, 0, stream>>>(
      QKV + 2097152, QKV, out, nullptr, x, gamma,
      3145728LL, 3145728LL, 1048576LL);
}

// Round 4
// 529.420 us; speedup vs baseline: 1.0492x; 1.0492x over previous
//
#include <hip/hip_runtime.h>
#include <cstdint>

typedef __fp16 f16x8 __attribute__((ext_vector_type(8)));
typedef __fp16 f16x4 __attribute__((ext_vector_type(4)));
typedef float  f32x4 __attribute__((ext_vector_type(4)));

static constexpr int NDIM = 1024;  // N = H*W = C = KC = VC

// ---------------- workspace layout (bytes) ----------------
static constexpr long long OFF_W     = 0;
static constexpr long long OFF_BIAS  = 6291456;
static constexpr long long OFF_XT    = 6303744;
static constexpr long long OFF_S     = 0;
static constexpr long long OFF_QKV   = 134217728;
static constexpr long long OFF_STATS = OFF_QKV + 2097152;  // over k[0]
// total required: OFF_QKV + 32*3072*1024*2 = 335,544,320 bytes

__device__ __forceinline__ void async16(__fp16* lds, const __fp16* g) {
  __builtin_amdgcn_global_load_lds(
      (const __attribute__((address_space(1))) void*)g,
      (__attribute__((address_space(3))) void*)lds, 16, 0, 0);
}

// ---------------- small prep kernels ----------------
__global__ __launch_bounds__(256) void cast_w(const float* __restrict__ Wq,
                                              const float* __restrict__ Wk,
                                              const float* __restrict__ Wv,
                                              __fp16* __restrict__ W3) {
  const int i = blockIdx.x * 256 + threadIdx.x;
  const int which = i >> 18;
  const int j = i & 262143;
  const float* src = which == 0 ? Wq : (which == 1 ? Wk : Wv);
  const float4 v = ((const float4*)src)[j];
  f16x4 o = {(__fp16)v.x, (__fp16)v.y, (__fp16)v.z, (__fp16)v.w};
  ((f16x4*)W3)[i] = o;
}

__global__ __launch_bounds__(256) void pack_bias(const float* __restrict__ bq,
                                                 const float* __restrict__ bk,
                                                 const float* __restrict__ bv,
                                                 float* __restrict__ b3) {
  const int i = blockIdx.x * 256 + threadIdx.x;
  if (i < 1024) b3[i] = bq[i];
  else if (i < 2048) b3[i] = bk[i - 1024];
  else if (i < 3072) b3[i] = bv[i - 2048];
}

__global__ __launch_bounds__(256) void transpose_cast_x(const float* __restrict__ x,
                                                        __fp16* __restrict__ xT) {
  __shared__ float t[32][33];
  const int b = blockIdx.z;
  const int n0 = blockIdx.x * 32, c0 = blockIdx.y * 32;
  const float* xb = x + (long long)b * NDIM * NDIM;
  __fp16* ob = xT + (long long)b * NDIM * NDIM;
  const int tx = threadIdx.x & 31, ty = threadIdx.x >> 5;
#pragma unroll
  for (int i = ty; i < 32; i += 8)
    t[i][tx] = xb[(long long)(c0 + i) * NDIM + n0 + tx];
  __syncthreads();
#pragma unroll
  for (int i = ty; i < 32; i += 8)
    ob[(long long)(n0 + i) * NDIM + c0 + tx] = (__fp16)t[tx][i];
}

// ---------------- 256x256 BK=32 quad-buffered gemm_bt (A[M][K] * B^T[N][K]) ----------------
// LDS: As/Bs [4 buf][256 rows][32 cols] fp16; 16B-slot swizzle slot = g ^ ((row>>1)&3)
// (verified 0 bank conflicts in R3). Pipeline: tile t reads buf t&3; stage tile t+3
// into buf (t+3)&3 (dead: tile t-1's reads lgkm-retired before tile t's barrier).
// ONE barrier + ONE counted vmcnt(8) per tile; reads+MFMA compiler-pipelined
// (fine-grained lgkmcnt) so LDS streaming overlaps MFMA within and across waves.

#define STAGE_A(NXT, KN)                                                            \
  async16(&As[(NXT)*8192 + tid*8],        A  + (long long)(m0 + sRow)       * 1024 + (KN) + sCol); \
  async16(&As[(NXT)*8192 + 4096 + tid*8], A  + (long long)(m0 + 128 + sRow) * 1024 + (KN) + sCol);

#define STAGE_B(NXT, KN)                                                            \
  async16(&Bs[(NXT)*8192 + tid*8],        Bp + (long long)(n0 + sRow)       * 1024 + (KN) + sCol); \
  async16(&Bs[(NXT)*8192 + 4096 + tid*8], Bp + (long long)(n0 + 128 + sRow) * 1024 + (KN) + sCol);

#define TILE(BUF, NXT, KN)                                                          \
  asm volatile("s_waitcnt vmcnt(8)" ::: "memory");                                  \
  __builtin_amdgcn_s_barrier();                                                     \
  STAGE_A(NXT, KN)                                                                  \
  STAGE_B(NXT, KN)                                                                  \
  bf[0] = *(const f16x8*)&Bs[(BUF)*8192 + bBase + 0*512];                           \
  bf[1] = *(const f16x8*)&Bs[(BUF)*8192 + bBase + 1*512];                           \
  _Pragma("unroll")                                                                 \
  for (int mf = 0; mf < 8; ++mf)                                                    \
    af[mf] = *(const f16x8*)&As[(BUF)*8192 + aBase + mf*512];                       \
  bf[2] = *(const f16x8*)&Bs[(BUF)*8192 + bBase + 2*512];                           \
  bf[3] = *(const f16x8*)&Bs[(BUF)*8192 + bBase + 3*512];                           \
  _Pragma("unroll")                                                                 \
  for (int mf = 0; mf < 8; ++mf) {                                                  \
    _Pragma("unroll")                                                               \
    for (int nf = 0; nf < 4; ++nf)                                                  \
      acc[mf][nf] = __builtin_amdgcn_mfma_f32_16x16x32_f16(af[mf], bf[nf], acc[mf][nf], 0, 0, 0); \
  }

template <int EPI>
__global__ __launch_bounds__(512, 2)
void gemm256(const __fp16* __restrict__ Ag, const __fp16* __restrict__ Bg,
             void* __restrict__ Cout, const float* __restrict__ bias,
             const float* __restrict__ X, const float* __restrict__ gamma,
             long long sA, long long sB, long long sC) {
  __shared__ alignas(16) __fp16 As[4 * 8192];
  __shared__ alignas(16) __fp16 Bs[4 * 8192];

  const int tid  = threadIdx.x;
  const int wid  = tid >> 6, lane = tid & 63;
  const int wm   = wid >> 2, wn = wid & 3;
  const int g    = lane >> 4, r = lane & 15;
  const int b    = blockIdx.z;
  const int m0   = blockIdx.y * 256;
  const int n0   = blockIdx.x * 256;

  const __fp16* A  = Ag + (long long)b * sA;
  const __fp16* Bp = Bg + (long long)b * sB;

  // staging source pre-swizzle (LDS dest linear): slot tid&3 of row tid>>2
  // holds source chunk (tid&3) ^ ((row>>1)&3); (row>>1)&3 == (tid>>3)&3.
  const int sRow = tid >> 2;
  const int sCol = ((tid & 3) ^ ((tid >> 3) & 3)) * 8;

  // fragment reads: k-chunk g of row R lives at slot g ^ ((R>>1)&3) = g ^ ((r>>1)&3).
  const int fcol  = (g ^ ((r >> 1) & 3)) * 8;
  const int aBase = (wm * 128 + r) * 32 + fcol;
  const int bBase = (wn * 64 + r) * 32 + fcol;

  f16x8 af[8];
  f16x8 bf[4];
  f32x4 acc[8][4];
#pragma unroll
  for (int i = 0; i < 8; ++i)
#pragma unroll
    for (int j = 0; j < 4; ++j) acc[i][j] = f32x4{0.f, 0.f, 0.f, 0.f};

  // prologue: stage tiles 0,1,2 into bufs 0,1,2 (order per tile: A,A,B,B)
  STAGE_A(0, 0)  STAGE_B(0, 0)
  STAGE_A(1, 32) STAGE_B(1, 32)
  STAGE_A(2, 64) STAGE_B(2, 64)

  for (int t0 = 0; t0 < 1024; t0 += 128) {  // 4 tiles (BK=32) per iteration
    const int ka  = t0 + 96;                // k of tile (t0/32)+3
    const int k0n = (ka < 1024) ? ka : 0;   // clamped prefetch: junk lands in a
    const int k1n = (ka + 32 < 1024) ? ka + 32 : 0;  // dead buffer, keeps vmcnt uniform
    const int k2n = (ka + 64 < 1024) ? ka + 64 : 0;
    const int k3n = (ka + 96 < 1024) ? ka + 96 : 0;
    TILE(0, 3, k0n)
    TILE(1, 0, k1n)
    TILE(2, 1, k2n)
    TILE(3, 2, k3n)
  }

  // epilogue: C/D layout col=lane&15, row=(lane>>4)*4+reg
  const float g2 = (EPI == 2) ? gamma[0] : 0.f;
  const int ccol  = n0 + wn * 64 + (lane & 15);
  const int crow0 = m0 + wm * 128 + (lane >> 4) * 4;
#pragma unroll
  for (int mf = 0; mf < 8; ++mf) {
#pragma unroll
    for (int reg = 0; reg < 4; ++reg) {
      const int row = crow0 + mf * 16 + reg;
      const long long rb = (long long)b * sC + (long long)row * 1024;
      const float bb = (EPI == 0) ? bias[row] : 0.f;
#pragma unroll
      for (int nf = 0; nf < 4; ++nf) {
        const int col = ccol + nf * 16;
        const float v = acc[mf][nf][reg];
        if (EPI == 0)      ((__fp16*)Cout)[rb + col] = (__fp16)(v + bb);
        else if (EPI == 1) ((float*)Cout)[rb + col] = v;
        else               ((float*)Cout)[rb + col] = g2 * v + X[rb + col];
      }
    }
  }
}

// ---------------- softmax ----------------
__global__ __launch_bounds__(256) void row_stats(const float* __restrict__ S,
                                                 float2* __restrict__ stats) {
  const int row = blockIdx.x * 4 + (threadIdx.x >> 6);
  const int lane = threadIdx.x & 63;
  const float4* rp = (const float4*)(S + (long long)row * NDIM);
  float4 v[4];
  float m = -3.4e38f;
#pragma unroll
  for (int j = 0; j < 4; j++) {
    v[j] = rp[lane + 64 * j];
    m = fmaxf(m, fmaxf(fmaxf(v[j].x, v[j].y), fmaxf(v[j].z, v[j].w)));
  }
#pragma unroll
  for (int o = 32; o; o >>= 1) m = fmaxf(m, __shfl_xor(m, o));
  float s = 0.f;
#pragma unroll
  for (int j = 0; j < 4; j++)
    s += __expf(v[j].x - m) + __expf(v[j].y - m) + __expf(v[j].z - m) + __expf(v[j].w - m);
#pragma unroll
  for (int o = 32; o; o >>= 1) s += __shfl_xor(s, o);
  if (lane == 0) stats[row] = make_float2(m, 1.f / s);
}

__global__ __launch_bounds__(256) void softmax_transpose(const float* __restrict__ S,
                                                         const float2* __restrict__ stats,
                                                         __fp16* __restrict__ attnT) {
  __shared__ __fp16 t[64][72];
  const int b = blockIdx.z;
  const int i0 = blockIdx.y * 64, j0 = blockIdx.x * 64;
  const float* Sb = S + (long long)b * NDIM * NDIM;
  const float2* st = stats + b * NDIM;
  const int tr = threadIdx.x >> 4;
  const int tc = (threadIdx.x & 15) * 4;
#pragma unroll
  for (int it = 0; it < 4; it++) {
    const int i = tr + 16 * it;
    const float4 vv = *(const float4*)&Sb[(long long)(i0 + i) * NDIM + j0 + tc];
    const float2 ms = st[i0 + i];
    t[tc + 0][i] = (__fp16)(__expf(vv.x - ms.x) * ms.y);
    t[tc + 1][i] = (__fp16)(__expf(vv.y - ms.x) * ms.y);
    t[tc + 2][i] = (__fp16)(__expf(vv.z - ms.x) * ms.y);
    t[tc + 3][i] = (__fp16)(__expf(vv.w - ms.x) * ms.y);
  }
  __syncthreads();
  __fp16* Ab = attnT + (long long)b * 3145728;
#pragma unroll
  for (int it = 0; it < 4; it++) {
    const int j = tr + 16 * it;
    f16x4 o = {t[j][tc], t[j][tc + 1], t[j][tc + 2], t[j][tc + 3]};
    *(f16x4*)&Ab[(long long)(j0 + j) * NDIM + i0 + tc] = o;
  }
}

// ---------------- launch ----------------
extern "C" void kernel_launch(void* const* d_in, const int* in_sizes, int n_in,
                              void* d_out, int out_size, void* d_ws, size_t ws_size,
                              hipStream_t stream) {
  const float* x     = (const float*)d_in[0];
  const float* Wq    = (const float*)d_in[1];
  const float* bq    = (const float*)d_in[2];
  const float* Wk    = (const float*)d_in[3];
  const float* bk    = (const float*)d_in[4];
  const float* Wv    = (const float*)d_in[5];
  const float* bv    = (const float*)d_in[6];
  const float* gamma = (const float*)d_in[7];
  char* ws = (char*)d_ws;

  __fp16* W3    = (__fp16*)(ws + OFF_W);
  float*  bias3 = (float*)(ws + OFF_BIAS);
  __fp16* xT    = (__fp16*)(ws + OFF_XT);
  float*  S     = (float*)(ws + OFF_S);
  __fp16* QKV   = (__fp16*)(ws + OFF_QKV);
  float2* stats = (float2*)(ws + OFF_STATS);
  float*  out   = (float*)d_out;

  cast_w<<<3072, 256, 0, stream>>>(Wq, Wk, Wv, W3);
  pack_bias<<<12, 256, 0, stream>>>(bq, bk, bv, bias3);
  transpose_cast_x<<<dim3(32, 32, 32), 256, 0, stream>>>(x, xT);

  // QKV[b] = W3 (3072x1024) * xT[b]^T  (+bias), fp16
  gemm256<0><<<dim3(4, 12, 32), 512, 0, stream>>>(
      W3, xT, QKV, bias3, nullptr, nullptr,
      0LL, 1048576LL, 3145728LL);

  // S[b] = q[b] * k[b]^T, f32
  gemm256<1><<<dim3(4, 4, 32), 512, 0, stream>>>(
      QKV, QKV + 1048576, S, nullptr, nullptr, nullptr,
      3145728LL, 3145728LL, 1048576LL);

  row_stats<<<8192, 256, 0, stream>>>(S, stats);
  softmax_transpose<<<dim3(16, 16, 32), 256, 0, stream>>>(S, stats, QKV);

  // out[b] = gamma * (v[b] * attnT[b]^T) + x[b], f32 -> d_out
  gemm256<2><<<dim3(4, 4, 32), 512, 0, stream>>>(
      QKV + 2097152, QKV, out, nullptr, x, gamma,
      3145728LL, 3145728LL, 1048576LL);
}